// Round 6
// baseline (363.280 us; speedup 1.0000x reference)
//
#include <hip/hip_runtime.h>
#include <hip/hip_bf16.h>

// 2-layer GraphSAGE mean-aggr, N=100000, E=1600000, F=128.
// R16: re-fuse layer 1 with R14's root cause fixed. R14 failed on occupancy
// (44KB LDS -> 2 blocks/CU -> gather issue rate halved; gather is
// service-rate bound and needs ~21+ waves/CU). v2: NO As/Bs staging --
// B-fragments read direct from global wt (64KB, L2-hot), x-side A direct
// from global xb (own rows). Only Ms[64][136] remains = 17.4KB LDS ->
// ~7 blocks/CU, ~28 waves/CU; GEMM phase has ZERO barriers (Ms read-only
// after one syncthreads), overlaps other blocks' gathers.
// mean1 never materialized (saves 25MB write + 25.6MB read + gemm1 dispatch).
// Layer 2 split as R15 (x,h can't both fit ws): h -> d_out ODD halves
// (transients dead after fill), mean2 -> xb (x dead after fused1),
// gemm2 reads mean2(xb,128)+h(d_out odd,256), writes fp32 full rows
// (own-rows aliasing, proven). Gather/pack/MFMA order identical ->
// bit-identical output. Chain kernels byte-identical to R15.

#define N_NODES 100000
#define N_EDGES 1600000
#define F 128
#define NBK 782       // ceil(N/128) buckets (128 nodes each)
#define NSB 391       // scatter blocks (4096 edges each)

typedef __attribute__((ext_vector_type(8))) short short8;
typedef __attribute__((ext_vector_type(4))) float f32x4;

__device__ __forceinline__ unsigned short f2bf(float f) {
    union { __hip_bfloat16 h; unsigned short u; } cv;
    cv.h = __float2bfloat16(f);
    return cv.u;
}
// unpack packed bf16 pair and accumulate
__device__ __forceinline__ void upadd(unsigned u, float& a, float& b) {
    a += __uint_as_float(u << 16);
    b += __uint_as_float(u & 0xffff0000u);
}

// ---------------- blkhist (transposed out) + wt, one dispatch ----------------
__global__ __launch_bounds__(256) void blkhist_wt_kernel(
    const int* __restrict__ dst, int* __restrict__ blkhist,
    const float* __restrict__ Wl1, const float* __restrict__ Wr1,
    const float* __restrict__ Wl2, const float* __restrict__ Wr2,
    unsigned short* __restrict__ wt, int E)
{
    __shared__ int h[NBK];
    int t = threadIdx.x, blk = blockIdx.x;
    if (blk < NSB) {
        for (int i = t; i < NBK; i += 256) h[i] = 0;
        __syncthreads();
        int base = blk * 4096;
        int end = min(base + 4096, E);
        for (int e = base + t; e < end; e += 256) atomicAdd(&h[dst[e] >> 7], 1);
        __syncthreads();
        for (int i = t; i < NBK; i += 256) blkhist[i * NSB + blk] = h[i];
    } else {
        int e = (blk - NSB) * 256 + t;   // 0..65535
        int layer = e >> 15;
        int idx = e & 32767;
        int k = idx >> 7;      // 0..255
        int c = idx & 127;
        const float* W = (layer == 0) ? (k < 128 ? Wl1 : Wr1)
                                      : (k < 128 ? Wl2 : Wr2);
        float v = W[(k & 127) * 128 + c];
        wt[layer * 32768 + c * 256 + k] = f2bf(v);
    }
}

// ---------------- bucket_scan: one WAVE per bucket, shfl scan ----------------
__global__ __launch_bounds__(256) void bucket_scan_kernel(
    const int* __restrict__ blkhist,   // [NBK][NSB]
    int* __restrict__ bbase,           // [NSB][NBK]
    int* __restrict__ btotal)
{
    int wv = threadIdx.x >> 6, lane = threadIdx.x & 63;
    int b = blockIdx.x * 4 + wv;
    if (b >= NBK) return;
    const int* row = blkhist + (size_t)b * NSB;
    int carry = 0;
    for (int base = 0; base < NSB; base += 64) {
        int t = base + lane;
        int v = (t < NSB) ? row[t] : 0;
        int s = v;
#pragma unroll
        for (int off = 1; off < 64; off <<= 1) {
            int u = __shfl_up(s, off);
            if (lane >= off) s += u;
        }
        if (t < NSB) bbase[t * NBK + b] = carry + s - v;   // exclusive, bucket-relative
        carry += __shfl(s, 63);
    }
    if (lane == 0) btotal[b] = carry;
}

// single block: exclusive scan of bucket totals in-place; bb[NBK] = E sentinel
__global__ __launch_bounds__(1024) void bucket_base_scan_kernel(int* bb)
{
    __shared__ int s[1024];
    int t = threadIdx.x;
    int v = (t < NBK) ? bb[t] : 0;
    s[t] = v;
    __syncthreads();
#pragma unroll
    for (int off = 1; off < 1024; off <<= 1) {
        int u = (t >= off) ? s[t - off] : 0;
        __syncthreads();
        s[t] += u;
        __syncthreads();
    }
    if (t <= NBK) bb[t] = (t == 0) ? 0 : s[t - 1];
}

// ---------------- scatter (+cast riding along), one dispatch ----------------
__global__ __launch_bounds__(256) void scatter_cast_kernel(
    const int* __restrict__ src, const int* __restrict__ dst,
    const int* __restrict__ bbase, const int* __restrict__ bucket_base,
    unsigned* __restrict__ staging,
    const float* __restrict__ x, unsigned short* __restrict__ xb,
    int E, int total4)
{
    __shared__ int cur[NBK];
    int t = threadIdx.x, blk = blockIdx.x;
    if (blk < NSB) {
        for (int i = t; i < NBK; i += 256)
            cur[i] = bbase[blk * NBK + i] + bucket_base[i];
        __syncthreads();
        int base = blk * 4096;
        int end = min(base + 4096, E);
        for (int e = base + t; e < end; e += 256) {
            int d = dst[e];
            int p = atomicAdd(&cur[d >> 7], 1);
            staging[p] = ((unsigned)src[e] << 7) | (unsigned)(d & 127);
        }
    } else {
        int i = (blk - NSB) * 256 + t;
        if (i < total4) {
            float4 v = ((const float4*)x)[i];
            unsigned lo = ((unsigned)f2bf(v.y) << 16) | f2bf(v.x);
            unsigned hi = ((unsigned)f2bf(v.w) << 16) | f2bf(v.z);
            ((uint2*)xb)[i] = make_uint2(lo, hi);
        }
    }
}

// pass 1: LDS-histogram the bucket's 128 node slots -> deg/rowptr; pass 2: fill
__global__ __launch_bounds__(256) void bucket_fill_kernel(
    const unsigned* __restrict__ staging, const int* __restrict__ bucket_base,
    int* __restrict__ rowptr, int* __restrict__ deg_i,
    int* __restrict__ csr_src, int N)
{
    __shared__ int cnt[128];
    __shared__ int sc[128];
    __shared__ int cur[128];
    int b = blockIdx.x;
    int t = threadIdx.x;
    if (t < 128) cnt[t] = 0;
    __syncthreads();
    int start = bucket_base[b];
    int end = bucket_base[b + 1];
    for (int e = start + t; e < end; e += 256)
        atomicAdd(&cnt[staging[e] & 127], 1);
    __syncthreads();
    if (t < 128) sc[t] = cnt[t];
    __syncthreads();
#pragma unroll
    for (int off = 1; off < 128; off <<= 1) {
        int v = (t < 128 && t >= off) ? sc[t - off] : 0;
        __syncthreads();
        if (t < 128) sc[t] += v;
        __syncthreads();
    }
    if (t < 128) {
        int excl = sc[t] - cnt[t];
        cur[t] = start + excl;
        int node = (b << 7) + t;
        if (node < N) {
            rowptr[node] = start + excl;
            deg_i[node] = cnt[t];
        }
    }
    __syncthreads();
    for (int e = start + t; e < end; e += 256) {
        unsigned u = staging[e];
        int p = atomicAdd(&cur[u & 127], 1);
        csr_src[p] = (int)(u >> 7);
    }
}

// ---------------- aggregate: mean over in-neighbors (bf16 src) ----------------
// One node per QUARTER-wave; lane c owns 16B (cols 8c..8c+7).
// SS = log2(src row pitch in uint4); SOF = src uint4 offset within row;
// DS = log2(dst row pitch in uint4).
template <int SS, int SOF, int DS>
__global__ __launch_bounds__(256) void csr_mean_kernel(
    const uint4* __restrict__ featb4, const int* __restrict__ rowptr,
    const int* __restrict__ deg_i, const int* __restrict__ csr_src,
    uint4* __restrict__ mean4, int N)
{
    int lane = threadIdx.x & 63;
    int wv = threadIdx.x >> 6;                     // wave in block 0..3
    int c = lane & 15;                             // 16B column segment
    int qb = lane & 48;                            // quarter's shfl base
    int n = blockIdx.x * 16 + wv * 4 + (lane >> 4);
    if (n >= N) return;
    int start = rowptr[n];
    int dg = deg_i[n];

    float acc[8];
#pragma unroll
    for (int j = 0; j < 8; ++j) acc[j] = 0.f;

    for (int base = 0; base < dg; base += 16) {
        int rem = min(dg - base, 16);
        int idxw = (c < rem) ? csr_src[start + base + c] : 0;

        int e = 0;
        for (; e + 4 <= rem; e += 4) {
            int i0 = __shfl(idxw, qb + e);
            int i1 = __shfl(idxw, qb + e + 1);
            int i2 = __shfl(idxw, qb + e + 2);
            int i3 = __shfl(idxw, qb + e + 3);
            uint4 u0 = featb4[(unsigned)((i0 << SS) + SOF + c)];
            uint4 u1 = featb4[(unsigned)((i1 << SS) + SOF + c)];
            uint4 u2 = featb4[(unsigned)((i2 << SS) + SOF + c)];
            uint4 u3 = featb4[(unsigned)((i3 << SS) + SOF + c)];
            upadd(u0.x, acc[0], acc[1]);
            upadd(u0.y, acc[2], acc[3]);
            upadd(u0.z, acc[4], acc[5]);
            upadd(u0.w, acc[6], acc[7]);
            upadd(u1.x, acc[0], acc[1]);
            upadd(u1.y, acc[2], acc[3]);
            upadd(u1.z, acc[4], acc[5]);
            upadd(u1.w, acc[6], acc[7]);
            upadd(u2.x, acc[0], acc[1]);
            upadd(u2.y, acc[2], acc[3]);
            upadd(u2.z, acc[4], acc[5]);
            upadd(u2.w, acc[6], acc[7]);
            upadd(u3.x, acc[0], acc[1]);
            upadd(u3.y, acc[2], acc[3]);
            upadd(u3.z, acc[4], acc[5]);
            upadd(u3.w, acc[6], acc[7]);
        }
        for (; e < rem; ++e) {
            int i0 = __shfl(idxw, qb + e);
            uint4 u0 = featb4[(unsigned)((i0 << SS) + SOF + c)];
            upadd(u0.x, acc[0], acc[1]);
            upadd(u0.y, acc[2], acc[3]);
            upadd(u0.z, acc[4], acc[5]);
            upadd(u0.w, acc[6], acc[7]);
        }
    }

    float r = 1.0f / fmaxf((float)dg, 1.0f);
    uint4 o;
    o.x = ((unsigned)f2bf(acc[1] * r) << 16) | f2bf(acc[0] * r);
    o.y = ((unsigned)f2bf(acc[3] * r) << 16) | f2bf(acc[2] * r);
    o.z = ((unsigned)f2bf(acc[5] * r) << 16) | f2bf(acc[4] * r);
    o.w = ((unsigned)f2bf(acc[7] * r) << 16) | f2bf(acc[6] * r);
    mean4[(unsigned)((n << DS) | c)] = o;
}

// ---------------- FUSED layer 1 v2: gather->Ms, barrier, barrier-free GEMM ----
// LDS = Ms only (17.4KB) -> ~7 blocks/CU, gather concurrency preserved.
// GEMM phase: A chunks 0-1 from Ms, chunks 2-3 direct from global xb (own
// rows); B direct from global wt (L2-hot). No As/Bs, no GEMM barriers.
// h -> d_out ODD halves: hb points at d_out shorts +128, pitch 256.
__global__ __launch_bounds__(256) void fused_sage1_kernel(
    const uint4* __restrict__ featb4,            // xb, 16 uint4/row
    const int* __restrict__ rowptr,
    const int* __restrict__ deg_i,
    const int* __restrict__ csr_src,
    const unsigned short* __restrict__ wt,       // layer1 [128 cols][256 k]
    const float* __restrict__ bias,
    unsigned short* __restrict__ hb,             // d_out shorts + 128, pitch 256
    int N)
{
    __shared__ unsigned short Ms[64][136];       // 272B stride: 2-way (free) on b128

    const int t = threadIdx.x;
    const int lane = t & 63;
    const int wv = t >> 6;
    const int c = lane & 15;
    const int qb = lane & 48;
    const int Q = wv * 4 + (lane >> 4);          // quarter id 0..15
    const int block_row = blockIdx.x * 64;

    // ---- gather phase (identical accumulation to split csr_mean) ----
    for (int j = 0; j < 4; ++j) {
        int row = Q * 4 + j;
        int n = block_row + row;
        if (n < N) {
            int start = rowptr[n];
            int dg = deg_i[n];
            float ga[8];
#pragma unroll
            for (int k = 0; k < 8; ++k) ga[k] = 0.f;

            for (int base = 0; base < dg; base += 16) {
                int rem = min(dg - base, 16);
                int idxw = (c < rem) ? csr_src[start + base + c] : 0;

                int e = 0;
                for (; e + 4 <= rem; e += 4) {
                    int i0 = __shfl(idxw, qb + e);
                    int i1 = __shfl(idxw, qb + e + 1);
                    int i2 = __shfl(idxw, qb + e + 2);
                    int i3 = __shfl(idxw, qb + e + 3);
                    uint4 u0 = featb4[(unsigned)((i0 << 4) | c)];
                    uint4 u1 = featb4[(unsigned)((i1 << 4) | c)];
                    uint4 u2 = featb4[(unsigned)((i2 << 4) | c)];
                    uint4 u3 = featb4[(unsigned)((i3 << 4) | c)];
                    upadd(u0.x, ga[0], ga[1]);
                    upadd(u0.y, ga[2], ga[3]);
                    upadd(u0.z, ga[4], ga[5]);
                    upadd(u0.w, ga[6], ga[7]);
                    upadd(u1.x, ga[0], ga[1]);
                    upadd(u1.y, ga[2], ga[3]);
                    upadd(u1.z, ga[4], ga[5]);
                    upadd(u1.w, ga[6], ga[7]);
                    upadd(u2.x, ga[0], ga[1]);
                    upadd(u2.y, ga[2], ga[3]);
                    upadd(u2.z, ga[4], ga[5]);
                    upadd(u2.w, ga[6], ga[7]);
                    upadd(u3.x, ga[0], ga[1]);
                    upadd(u3.y, ga[2], ga[3]);
                    upadd(u3.z, ga[4], ga[5]);
                    upadd(u3.w, ga[6], ga[7]);
                }
                for (; e < rem; ++e) {
                    int i0 = __shfl(idxw, qb + e);
                    uint4 u0 = featb4[(unsigned)((i0 << 4) | c)];
                    upadd(u0.x, ga[0], ga[1]);
                    upadd(u0.y, ga[2], ga[3]);
                    upadd(u0.z, ga[4], ga[5]);
                    upadd(u0.w, ga[6], ga[7]);
                }
            }

            float r = 1.0f / fmaxf((float)dg, 1.0f);
            uint4 o;
            o.x = ((unsigned)f2bf(ga[1] * r) << 16) | f2bf(ga[0] * r);
            o.y = ((unsigned)f2bf(ga[3] * r) << 16) | f2bf(ga[2] * r);
            o.z = ((unsigned)f2bf(ga[5] * r) << 16) | f2bf(ga[4] * r);
            o.w = ((unsigned)f2bf(ga[7] * r) << 16) | f2bf(ga[6] * r);
            *(uint4*)&Ms[row][c * 8] = o;
        } else {
            *(uint4*)&Ms[row][c * 8] = make_uint4(0, 0, 0, 0);
        }
    }
    __syncthreads();

    // ---- GEMM phase (no barriers, no LDS staging) ----
    const unsigned short* xin = (const unsigned short*)featb4;
    const int m = lane & 15;
    const int kq = lane >> 4;
    const int arow = block_row + wv * 16 + m;
    const bool arow_ok = (arow < N);

    f32x4 acc[8];
#pragma unroll
    for (int i = 0; i < 8; ++i) acc[i] = (f32x4){0.f, 0.f, 0.f, 0.f};

#pragma unroll
    for (int chunk = 0; chunk < 4; ++chunk) {
#pragma unroll
        for (int ks = 0; ks < 2; ++ks) {
            short8 a;
            if (chunk < 2) {
                a = *(const short8*)&Ms[wv * 16 + m][chunk * 64 + ks * 32 + kq * 8];
            } else {
                a = (short8){0,0,0,0,0,0,0,0};
                if (arow_ok)
                    a = *(const short8*)(xin + (size_t)arow * F
                                         + (chunk - 2) * 64 + ks * 32 + kq * 8);
            }
#pragma unroll
            for (int tt = 0; tt < 8; ++tt) {
                short8 b = *(const short8*)(wt + (tt * 16 + m) * 256
                                            + chunk * 64 + ks * 32 + kq * 8);
                acc[tt] = __builtin_amdgcn_mfma_f32_16x16x32_bf16(a, b, acc[tt], 0, 0, 0);
            }
        }
    }

    // ---- epilogue: relu + bf16 h -> d_out odd halves ----
    float bb[8];
#pragma unroll
    for (int tt = 0; tt < 8; ++tt) bb[tt] = bias[tt * 16 + m];
    int rbase = block_row + wv * 16 + kq * 4;
#pragma unroll
    for (int r = 0; r < 4; ++r) {
        int grow = rbase + r;
        if (grow < N) {
#pragma unroll
            for (int tt = 0; tt < 8; ++tt) {
                float v = fmaxf(acc[tt][r] + bb[tt], 0.f);
                hb[(size_t)grow * 256 + tt * 16 + m] = f2bf(v);
            }
        }
    }
}

// ---------------- MFMA GEMM (layer 2): out = mean2 @ Wl + h @ Wr + b ----------
// MP/XP/OP: row pitches (in elems) of mean, x-input, output.
template <bool RELU, bool OUT_BF16, int MP, int XP, int OP>
__global__ __launch_bounds__(256) void sage_gemm_mfma(
    const unsigned short* __restrict__ meanb,
    const unsigned short* __restrict__ xin,
    const unsigned short* __restrict__ wt,   // [128 cols][256 k] bf16
    const float* __restrict__ bias,
    float* __restrict__ outp, unsigned short* __restrict__ outb, int N)
{
    __shared__ unsigned short As[64][72];    // stride 144 B: conflict-free b128
    __shared__ unsigned short Bs[128][72];

    const int t = threadIdx.x;
    const int block_row = blockIdx.x * 64;
    const int lane = t & 63;
    const int w = t >> 6;
    const int m = lane & 15;
    const int kq = lane >> 4;

    f32x4 acc[8];
#pragma unroll
    for (int i = 0; i < 8; ++i) acc[i] = (f32x4){0.f, 0.f, 0.f, 0.f};

    for (int chunk = 0; chunk < 4; ++chunk) {
        const bool is_mean = (chunk < 2);
        const int kbase = (chunk & 1) * 64;

        {
            int row_l = t >> 2;
            int seg = t & 3;
            int grow = block_row + row_l;
            unsigned short* dstp = &As[row_l][seg * 16];
            if (grow < N) {
                const unsigned short* srcp = is_mean
                    ? meanb + (size_t)grow * MP + kbase + seg * 16
                    : xin   + (size_t)grow * XP + kbase + seg * 16;
                const uint4* p = (const uint4*)srcp;
                ((uint4*)dstp)[0] = p[0];
                ((uint4*)dstp)[1] = p[1];
            } else {
                uint4 z = make_uint4(0, 0, 0, 0);
                ((uint4*)dstp)[0] = z;
                ((uint4*)dstp)[1] = z;
            }
        }
        {
            int c = t >> 1;
            int half = t & 1;
            const uint4* p = (const uint4*)(wt + c * 256 + chunk * 64 + half * 32);
            unsigned short* dstp = &Bs[c][half * 32];
            ((uint4*)dstp)[0] = p[0];
            ((uint4*)dstp)[1] = p[1];
            ((uint4*)dstp)[2] = p[2];
            ((uint4*)dstp)[3] = p[3];
        }
        __syncthreads();

#pragma unroll
        for (int ks = 0; ks < 2; ++ks) {
            short8 a = *(const short8*)&As[w * 16 + m][ks * 32 + kq * 8];
#pragma unroll
            for (int tt = 0; tt < 8; ++tt) {
                short8 b = *(const short8*)&Bs[tt * 16 + m][ks * 32 + kq * 8];
                acc[tt] = __builtin_amdgcn_mfma_f32_16x16x32_bf16(a, b, acc[tt], 0, 0, 0);
            }
        }
        __syncthreads();
    }

    float bb[8];
#pragma unroll
    for (int tt = 0; tt < 8; ++tt) bb[tt] = bias[tt * 16 + m];
    int rbase = block_row + w * 16 + kq * 4;
#pragma unroll
    for (int r = 0; r < 4; ++r) {
        int grow = rbase + r;
        if (grow < N) {
#pragma unroll
            for (int tt = 0; tt < 8; ++tt) {
                float v = acc[tt][r] + bb[tt];
                if (RELU) v = fmaxf(v, 0.f);
                if (OUT_BF16)
                    outb[(size_t)grow * OP + tt * 16 + m] = f2bf(v);
                else
                    outp[(size_t)grow * OP + tt * 16 + m] = v;
            }
        }
    }
}

extern "C" void kernel_launch(void* const* d_in, const int* in_sizes, int n_in,
                              void* d_out, int out_size, void* d_ws, size_t ws_size,
                              hipStream_t stream) {
    const float* x    = (const float*)d_in[0];
    const int*   ei   = (const int*)d_in[1];    // int32 (harness converts int64)
    const float* W_l1 = (const float*)d_in[2];
    const float* W_r1 = (const float*)d_in[3];
    const float* b1   = (const float*)d_in[4];
    const float* W_l2 = (const float*)d_in[5];
    const float* W_r2 = (const float*)d_in[6];
    const float* b2   = (const float*)d_in[7];
    float* out        = (float*)d_out;

    const int N = N_NODES;
    const int E = N_EDGES;
    const int* srcv = ei;
    const int* dstv = ei + E;

    // ---- workspace layout (bytes); ws_size proven >= 33,337,344 ----
    const size_t rowptr_off = 400128;            // int[N]
    const size_t bb_off     = 800256;            // bucket_base int[NBK+1]
    const size_t csr_off    = 804352;            // int[1.6M] -> 7,204,352
    const size_t xb_off     = 7204352;           // bf16[N*F] -> 32,804,352
    const size_t wt_off     = 32804352;          // bf16[2][128][256] -> 32,935,424
    const size_t need_min   = 32935424;
    // transients aliased into d_out (dead after bucket_fill; h odd-halves
    // written by fused1 afterwards):
    const size_t blkh_rel   = 0;                 // int[NBK*NSB]
    const size_t bbase_rel  = 1223168;           // int[NSB*NBK]
    const size_t stag_rel   = 2446336;           // uint[1.6M] -> 8,846,336

    if (ws_size < need_min) return;  // clean validation failure as diagnostic

    char* ws = (char*)d_ws;
    int* deg_i   = (int*)ws;
    int* rowptr  = (int*)(ws + rowptr_off);
    int* bucket_base = (int*)(ws + bb_off);
    int* csr_src = (int*)(ws + csr_off);
    unsigned short* xb = (unsigned short*)(ws + xb_off);
    unsigned short* wt = (unsigned short*)(ws + wt_off);
    char* dob = (char*)d_out;
    int* blkhist = (int*)(dob + blkh_rel);
    int* bbase   = (int*)(dob + bbase_rel);
    unsigned* staging = (unsigned*)(dob + stag_rel);
    // h lives in d_out ODD halves: row n -> bytes [512n+256, 512n+512)
    unsigned short* hb = (unsigned short*)d_out + 128;

    const int total4 = N * F / 4;                // 3,200,000 float4s
    const int cast_blocks = total4 / 256;        // 12500

    // ---- bucket permute chain (transients in d_out), wt+cast riding along ----
    blkhist_wt_kernel<<<dim3(NSB + 256), dim3(256), 0, stream>>>(
        dstv, blkhist, W_l1, W_r1, W_l2, W_r2, wt, E);
    bucket_scan_kernel<<<dim3((NBK + 3) / 4), dim3(256), 0, stream>>>(
        blkhist, bbase, bucket_base);
    bucket_base_scan_kernel<<<dim3(1), dim3(1024), 0, stream>>>(bucket_base);
    scatter_cast_kernel<<<dim3(NSB + cast_blocks), dim3(256), 0, stream>>>(
        srcv, dstv, bbase, bucket_base, staging, x, xb, E, total4);
    bucket_fill_kernel<<<dim3(NBK), dim3(256), 0, stream>>>(
        staging, bucket_base, rowptr, deg_i, csr_src, N);

    dim3 ablock(256), agrid((N + 15) / 16);
    dim3 gblock(256), ggrid((N + 63) / 64);

    // ---- layer 1 FUSED v2: gather(xb)->Ms + barrier-free GEMM -> h odd halves ----
    fused_sage1_kernel<<<ggrid, gblock, 0, stream>>>(
        (const uint4*)xb, rowptr, deg_i, csr_src, wt, b1, hb, N);

    // ---- layer 2: mean2(h @ d_out odd) -> xb contiguous; gemm2 -> fp32 d_out ----
    csr_mean_kernel<5, 16, 4><<<agrid, ablock, 0, stream>>>(
        (const uint4*)d_out, rowptr, deg_i, csr_src, (uint4*)xb, N);
    sage_gemm_mfma<false, false, 128, 256, 128><<<ggrid, gblock, 0, stream>>>(
        xb, hb, wt + 32768, b2, out, nullptr, N);
}

// Round 7
// 317.265 us; speedup vs baseline: 1.1450x; 1.1450x over previous
//
#include <hip/hip_runtime.h>
#include <hip/hip_bf16.h>

// 2-layer GraphSAGE mean-aggr, N=100000, E=1600000, F=128.
// R17: revert fusion permanently (R14: LDS-occupancy collapse; R16: 4x less
// node concurrency from j-loop serialization -- gather needs max waves).
// Back to R15 split structure, attack the CSR-build chain's scattered-write
// false sharing: with 782 buckets, each (block,bucket) staging run is ~20B,
// so every 64B line is shared by ~3 blocks on different XCDs -> write-through
// amplification (the R10-hist mechanism). Buckets enlarged 128 -> 512 nodes
// (NBK 782->196): runs ~84B > line -> L2 write-back coalesces; blkhist
// transposed writes shrink 4x. bucket_fill reworked for 512-node buckets
// (cnt/cur[512], 2-elem/thread scan, 32KB csr window = single-XCD L2-local).
// Encoding (src<<9)|(d&511), 26 bits. Means/GEMMs byte-identical to R15.

#define N_NODES 100000
#define N_EDGES 1600000
#define F 128
#define NBK 196       // ceil(N/512) buckets (512 nodes each)
#define NSB 391       // scatter blocks (4096 edges each)

typedef __attribute__((ext_vector_type(8))) short short8;
typedef __attribute__((ext_vector_type(4))) float f32x4;

__device__ __forceinline__ unsigned short f2bf(float f) {
    union { __hip_bfloat16 h; unsigned short u; } cv;
    cv.h = __float2bfloat16(f);
    return cv.u;
}
// unpack packed bf16 pair and accumulate
__device__ __forceinline__ void upadd(unsigned u, float& a, float& b) {
    a += __uint_as_float(u << 16);
    b += __uint_as_float(u & 0xffff0000u);
}

// ---------------- blkhist (transposed out) + wt, one dispatch ----------------
__global__ __launch_bounds__(256) void blkhist_wt_kernel(
    const int* __restrict__ dst, int* __restrict__ blkhist,
    const float* __restrict__ Wl1, const float* __restrict__ Wr1,
    const float* __restrict__ Wl2, const float* __restrict__ Wr2,
    unsigned short* __restrict__ wt, int E)
{
    __shared__ int h[NBK];
    int t = threadIdx.x, blk = blockIdx.x;
    if (blk < NSB) {
        for (int i = t; i < NBK; i += 256) h[i] = 0;
        __syncthreads();
        int base = blk * 4096;
        int end = min(base + 4096, E);
        for (int e = base + t; e < end; e += 256) atomicAdd(&h[dst[e] >> 9], 1);
        __syncthreads();
        for (int i = t; i < NBK; i += 256) blkhist[i * NSB + blk] = h[i];
    } else {
        int e = (blk - NSB) * 256 + t;   // 0..65535
        int layer = e >> 15;
        int idx = e & 32767;
        int k = idx >> 7;      // 0..255
        int c = idx & 127;
        const float* W = (layer == 0) ? (k < 128 ? Wl1 : Wr1)
                                      : (k < 128 ? Wl2 : Wr2);
        float v = W[(k & 127) * 128 + c];
        wt[layer * 32768 + c * 256 + k] = f2bf(v);
    }
}

// ---------------- bucket_scan: one WAVE per bucket, shfl scan ----------------
__global__ __launch_bounds__(256) void bucket_scan_kernel(
    const int* __restrict__ blkhist,   // [NBK][NSB]
    int* __restrict__ bbase,           // [NSB][NBK]
    int* __restrict__ btotal)
{
    int wv = threadIdx.x >> 6, lane = threadIdx.x & 63;
    int b = blockIdx.x * 4 + wv;
    if (b >= NBK) return;
    const int* row = blkhist + (size_t)b * NSB;
    int carry = 0;
    for (int base = 0; base < NSB; base += 64) {
        int t = base + lane;
        int v = (t < NSB) ? row[t] : 0;
        int s = v;
#pragma unroll
        for (int off = 1; off < 64; off <<= 1) {
            int u = __shfl_up(s, off);
            if (lane >= off) s += u;
        }
        if (t < NSB) bbase[t * NBK + b] = carry + s - v;   // exclusive, bucket-relative
        carry += __shfl(s, 63);
    }
    if (lane == 0) btotal[b] = carry;
}

// single block: exclusive scan of bucket totals in-place; bb[NBK] = E sentinel
__global__ __launch_bounds__(1024) void bucket_base_scan_kernel(int* bb)
{
    __shared__ int s[1024];
    int t = threadIdx.x;
    int v = (t < NBK) ? bb[t] : 0;
    s[t] = v;
    __syncthreads();
#pragma unroll
    for (int off = 1; off < 1024; off <<= 1) {
        int u = (t >= off) ? s[t - off] : 0;
        __syncthreads();
        s[t] += u;
        __syncthreads();
    }
    if (t <= NBK) bb[t] = (t == 0) ? 0 : s[t - 1];
}

// ---------------- scatter (+cast riding along), one dispatch ----------------
__global__ __launch_bounds__(256) void scatter_cast_kernel(
    const int* __restrict__ src, const int* __restrict__ dst,
    const int* __restrict__ bbase, const int* __restrict__ bucket_base,
    unsigned* __restrict__ staging,
    const float* __restrict__ x, unsigned short* __restrict__ xb,
    int E, int total4)
{
    __shared__ int cur[NBK];
    int t = threadIdx.x, blk = blockIdx.x;
    if (blk < NSB) {
        for (int i = t; i < NBK; i += 256)
            cur[i] = bbase[blk * NBK + i] + bucket_base[i];
        __syncthreads();
        int base = blk * 4096;
        int end = min(base + 4096, E);
        for (int e = base + t; e < end; e += 256) {
            int d = dst[e];
            int p = atomicAdd(&cur[d >> 9], 1);
            staging[p] = ((unsigned)src[e] << 9) | (unsigned)(d & 511);
        }
    } else {
        int i = (blk - NSB) * 256 + t;
        if (i < total4) {
            float4 v = ((const float4*)x)[i];
            unsigned lo = ((unsigned)f2bf(v.y) << 16) | f2bf(v.x);
            unsigned hi = ((unsigned)f2bf(v.w) << 16) | f2bf(v.z);
            ((uint2*)xb)[i] = make_uint2(lo, hi);
        }
    }
}

// pass 1: LDS-histogram the bucket's 512 node slots -> deg/rowptr; pass 2: fill
__global__ __launch_bounds__(256) void bucket_fill_kernel(
    const unsigned* __restrict__ staging, const int* __restrict__ bucket_base,
    int* __restrict__ rowptr, int* __restrict__ deg_i,
    int* __restrict__ csr_src, int N)
{
    __shared__ int cnt[512];
    __shared__ int sc[256];
    __shared__ int cur[512];
    int b = blockIdx.x;
    int t = threadIdx.x;
    for (int i = t; i < 512; i += 256) cnt[i] = 0;
    __syncthreads();
    int start = bucket_base[b];
    int end = bucket_base[b + 1];
    for (int e = start + t; e < end; e += 256)
        atomicAdd(&cnt[staging[e] & 511], 1);
    __syncthreads();
    // exclusive scan over 512 slot counts: 2 elems/thread
    int a0 = cnt[2 * t], a1 = cnt[2 * t + 1];
    int ps = a0 + a1;
    sc[t] = ps;
    __syncthreads();
#pragma unroll
    for (int off = 1; off < 256; off <<= 1) {
        int v = (t >= off) ? sc[t - off] : 0;
        __syncthreads();
        sc[t] += v;
        __syncthreads();
    }
    int excl = sc[t] - ps;                 // exclusive over pairs
    cur[2 * t]     = start + excl;
    cur[2 * t + 1] = start + excl + a0;
    int node0 = (b << 9) + 2 * t;
    if (node0 < N)     { rowptr[node0]     = start + excl;      deg_i[node0]     = a0; }
    if (node0 + 1 < N) { rowptr[node0 + 1] = start + excl + a0; deg_i[node0 + 1] = a1; }
    __syncthreads();
    for (int e = start + t; e < end; e += 256) {
        unsigned u = staging[e];
        int p = atomicAdd(&cur[u & 511], 1);
        csr_src[p] = (int)(u >> 9);
    }
}

// ---------------- aggregate: mean over in-neighbors (bf16 src) ----------------
// One node per QUARTER-wave; lane c owns 16B (cols 8c..8c+7).
// SS = log2(src row pitch in uint4); DS = log2(dst row pitch in uint4).
template <int SS, int DS>
__global__ __launch_bounds__(256) void csr_mean_kernel(
    const uint4* __restrict__ featb4, const int* __restrict__ rowptr,
    const int* __restrict__ deg_i, const int* __restrict__ csr_src,
    uint4* __restrict__ mean4, int N)
{
    int lane = threadIdx.x & 63;
    int wv = threadIdx.x >> 6;                     // wave in block 0..3
    int c = lane & 15;                             // 16B column segment
    int qb = lane & 48;                            // quarter's shfl base
    int n = blockIdx.x * 16 + wv * 4 + (lane >> 4);
    if (n >= N) return;
    int start = rowptr[n];
    int dg = deg_i[n];

    float acc[8];
#pragma unroll
    for (int j = 0; j < 8; ++j) acc[j] = 0.f;

    for (int base = 0; base < dg; base += 16) {
        int rem = min(dg - base, 16);
        int idxw = (c < rem) ? csr_src[start + base + c] : 0;

        int e = 0;
        for (; e + 4 <= rem; e += 4) {
            int i0 = __shfl(idxw, qb + e);
            int i1 = __shfl(idxw, qb + e + 1);
            int i2 = __shfl(idxw, qb + e + 2);
            int i3 = __shfl(idxw, qb + e + 3);
            uint4 u0 = featb4[(unsigned)((i0 << SS) | c)];
            uint4 u1 = featb4[(unsigned)((i1 << SS) | c)];
            uint4 u2 = featb4[(unsigned)((i2 << SS) | c)];
            uint4 u3 = featb4[(unsigned)((i3 << SS) | c)];
            upadd(u0.x, acc[0], acc[1]);
            upadd(u0.y, acc[2], acc[3]);
            upadd(u0.z, acc[4], acc[5]);
            upadd(u0.w, acc[6], acc[7]);
            upadd(u1.x, acc[0], acc[1]);
            upadd(u1.y, acc[2], acc[3]);
            upadd(u1.z, acc[4], acc[5]);
            upadd(u1.w, acc[6], acc[7]);
            upadd(u2.x, acc[0], acc[1]);
            upadd(u2.y, acc[2], acc[3]);
            upadd(u2.z, acc[4], acc[5]);
            upadd(u2.w, acc[6], acc[7]);
            upadd(u3.x, acc[0], acc[1]);
            upadd(u3.y, acc[2], acc[3]);
            upadd(u3.z, acc[4], acc[5]);
            upadd(u3.w, acc[6], acc[7]);
        }
        for (; e < rem; ++e) {
            int i0 = __shfl(idxw, qb + e);
            uint4 u0 = featb4[(unsigned)((i0 << SS) | c)];
            upadd(u0.x, acc[0], acc[1]);
            upadd(u0.y, acc[2], acc[3]);
            upadd(u0.z, acc[4], acc[5]);
            upadd(u0.w, acc[6], acc[7]);
        }
    }

    float r = 1.0f / fmaxf((float)dg, 1.0f);
    uint4 o;
    o.x = ((unsigned)f2bf(acc[1] * r) << 16) | f2bf(acc[0] * r);
    o.y = ((unsigned)f2bf(acc[3] * r) << 16) | f2bf(acc[2] * r);
    o.z = ((unsigned)f2bf(acc[5] * r) << 16) | f2bf(acc[4] * r);
    o.w = ((unsigned)f2bf(acc[7] * r) << 16) | f2bf(acc[6] * r);
    mean4[(unsigned)((n << DS) | c)] = o;
}

// ---------------- MFMA GEMM: out = mean @ Wl + x @ Wr + b (+relu) ----------------
// MP/XP/OP: row pitches (in elems) of mean, x-input, output.
// Aliasing-safe: block reads ONLY its own rows; epilogue writes those same
// rows after all reads (ordered by __syncthreads within block).
template <bool RELU, bool OUT_BF16, int MP, int XP, int OP>
__global__ __launch_bounds__(256) void sage_gemm_mfma(
    const unsigned short* __restrict__ meanb,
    const unsigned short* __restrict__ xin,
    const unsigned short* __restrict__ wt,   // [128 cols][256 k] bf16
    const float* __restrict__ bias,
    float* __restrict__ outp, unsigned short* __restrict__ outb, int N)
{
    __shared__ unsigned short As[64][72];    // stride 144 B: conflict-free b128
    __shared__ unsigned short Bs[128][72];

    const int t = threadIdx.x;
    const int block_row = blockIdx.x * 64;
    const int lane = t & 63;
    const int w = t >> 6;
    const int m = lane & 15;
    const int kq = lane >> 4;

    f32x4 acc[8];
#pragma unroll
    for (int i = 0; i < 8; ++i) acc[i] = (f32x4){0.f, 0.f, 0.f, 0.f};

    for (int chunk = 0; chunk < 4; ++chunk) {
        const bool is_mean = (chunk < 2);
        const int kbase = (chunk & 1) * 64;

        {
            int row_l = t >> 2;
            int seg = t & 3;
            int grow = block_row + row_l;
            unsigned short* dstp = &As[row_l][seg * 16];
            if (grow < N) {
                const unsigned short* srcp = is_mean
                    ? meanb + (size_t)grow * MP + kbase + seg * 16
                    : xin   + (size_t)grow * XP + kbase + seg * 16;
                const uint4* p = (const uint4*)srcp;
                ((uint4*)dstp)[0] = p[0];
                ((uint4*)dstp)[1] = p[1];
            } else {
                uint4 z = make_uint4(0, 0, 0, 0);
                ((uint4*)dstp)[0] = z;
                ((uint4*)dstp)[1] = z;
            }
        }
        {
            int c = t >> 1;
            int half = t & 1;
            const uint4* p = (const uint4*)(wt + c * 256 + chunk * 64 + half * 32);
            unsigned short* dstp = &Bs[c][half * 32];
            ((uint4*)dstp)[0] = p[0];
            ((uint4*)dstp)[1] = p[1];
            ((uint4*)dstp)[2] = p[2];
            ((uint4*)dstp)[3] = p[3];
        }
        __syncthreads();

#pragma unroll
        for (int ks = 0; ks < 2; ++ks) {
            short8 a = *(const short8*)&As[w * 16 + m][ks * 32 + kq * 8];
#pragma unroll
            for (int tt = 0; tt < 8; ++tt) {
                short8 b = *(const short8*)&Bs[tt * 16 + m][ks * 32 + kq * 8];
                acc[tt] = __builtin_amdgcn_mfma_f32_16x16x32_bf16(a, b, acc[tt], 0, 0, 0);
            }
        }
        __syncthreads();
    }

    float bb[8];
#pragma unroll
    for (int tt = 0; tt < 8; ++tt) bb[tt] = bias[tt * 16 + m];
    int rbase = block_row + w * 16 + kq * 4;
#pragma unroll
    for (int r = 0; r < 4; ++r) {
        int grow = rbase + r;
        if (grow < N) {
#pragma unroll
            for (int tt = 0; tt < 8; ++tt) {
                float v = acc[tt][r] + bb[tt];
                if (RELU) v = fmaxf(v, 0.f);
                if (OUT_BF16)
                    outb[(size_t)grow * OP + tt * 16 + m] = f2bf(v);
                else
                    outp[(size_t)grow * OP + tt * 16 + m] = v;
            }
        }
    }
}

extern "C" void kernel_launch(void* const* d_in, const int* in_sizes, int n_in,
                              void* d_out, int out_size, void* d_ws, size_t ws_size,
                              hipStream_t stream) {
    const float* x    = (const float*)d_in[0];
    const int*   ei   = (const int*)d_in[1];    // int32 (harness converts int64)
    const float* W_l1 = (const float*)d_in[2];
    const float* W_r1 = (const float*)d_in[3];
    const float* b1   = (const float*)d_in[4];
    const float* W_l2 = (const float*)d_in[5];
    const float* W_r2 = (const float*)d_in[6];
    const float* b2   = (const float*)d_in[7];
    float* out        = (float*)d_out;

    const int N = N_NODES;
    const int E = N_EDGES;
    const int* srcv = ei;
    const int* dstv = ei + E;

    // ---- workspace layout (bytes); ws_size proven >= 33,337,344 ----
    const size_t rowptr_off = 400128;            // int[N]
    const size_t bb_off     = 800256;            // bucket_base int[NBK+1]
    const size_t csr_off    = 804352;            // int[1.6M] -> 7,204,352
    const size_t xb_off     = 7204352;           // bf16[N*F] -> 32,804,352
    const size_t wt_off     = 32804352;          // bf16[2][128][256] -> 32,935,424
    const size_t need_min   = 32935424;
    // transients aliased into d_out (dead after bucket_fill):
    const size_t blkh_rel   = 0;                 // int[NBK*NSB] = 306,544
    const size_t bbase_rel  = 1223168;           // int[NSB*NBK] = 306,544
    const size_t stag_rel   = 2446336;           // uint[1.6M] -> 8,846,336

    if (ws_size < need_min) return;  // clean validation failure as diagnostic

    char* ws = (char*)d_ws;
    int* deg_i   = (int*)ws;
    int* rowptr  = (int*)(ws + rowptr_off);
    int* bucket_base = (int*)(ws + bb_off);
    int* csr_src = (int*)(ws + csr_off);
    unsigned short* xb = (unsigned short*)(ws + xb_off);
    unsigned short* wt = (unsigned short*)(ws + wt_off);
    char* dob = (char*)d_out;
    int* blkhist = (int*)(dob + blkh_rel);
    int* bbase   = (int*)(dob + bbase_rel);
    unsigned* staging = (unsigned*)(dob + stag_rel);
    // means live interleaved in d_out: row n -> bytes [n*512, n*512+256)
    uint4* mean4 = (uint4*)d_out;
    const unsigned short* meanb = (const unsigned short*)d_out;

    const int total4 = N * F / 4;                // 3,200,000 float4s
    const int cast_blocks = total4 / 256;        // 12500

    // ---- bucket permute chain (transients in d_out), wt+cast riding along ----
    blkhist_wt_kernel<<<dim3(NSB + 256), dim3(256), 0, stream>>>(
        dstv, blkhist, W_l1, W_r1, W_l2, W_r2, wt, E);
    bucket_scan_kernel<<<dim3((NBK + 3) / 4), dim3(256), 0, stream>>>(
        blkhist, bbase, bucket_base);
    bucket_base_scan_kernel<<<dim3(1), dim3(1024), 0, stream>>>(bucket_base);
    scatter_cast_kernel<<<dim3(NSB + cast_blocks), dim3(256), 0, stream>>>(
        srcv, dstv, bbase, bucket_base, staging, x, xb, E, total4);
    bucket_fill_kernel<<<dim3(NBK), dim3(256), 0, stream>>>(
        staging, bucket_base, rowptr, deg_i, csr_src, N);

    dim3 ablock(256), agrid((N + 15) / 16);
    dim3 gblock(256), ggrid((N + 63) / 64);

    // ---- layer 1: mean1(xb) -> d_out interleaved; gemm1 -> h bf16 into xb ----
    csr_mean_kernel<4, 5><<<agrid, ablock, 0, stream>>>(
        (const uint4*)xb, rowptr, deg_i, csr_src, mean4, N);
    sage_gemm_mfma<true, true, 256, 128, 128><<<ggrid, gblock, 0, stream>>>(
        meanb, xb, wt, b1, nullptr, xb, N);

    // ---- layer 2: mean2(xb=h) -> d_out interleaved; gemm2 -> fp32 d_out ----
    csr_mean_kernel<4, 5><<<agrid, ablock, 0, stream>>>(
        (const uint4*)xb, rowptr, deg_i, csr_src, mean4, N);
    sage_gemm_mfma<false, false, 256, 128, 128><<<ggrid, gblock, 0, stream>>>(
        meanb, xb, wt + 32768, b2, out, nullptr, N);
}